// Round 1
// baseline (9578.320 us; speedup 1.0000x reference)
//
#include <hip/hip_runtime.h>
#include <hip/hip_bf16.h>

#define HDIM 128
#define GDIM 512   // 4*H
#define TDIM 2048
#define BDIM 256
#define CHUNK 16
#define NT 512

__device__ __forceinline__ float sigm_f(float x) {
    return 1.0f / (1.0f + __expf(-x));
}
__device__ __forceinline__ float tanh_f(float x) {
    // tanh(x) = 1 - 2/(1+exp(2x)); saturates correctly at +-inf
    return 1.0f - 2.0f / (1.0f + __expf(2.0f * x));
}

__global__ __launch_bounds__(NT, 2)
void lstm3_kernel(const float* __restrict__ x,
                  const float* __restrict__ Wih0, const float* __restrict__ Whh0,
                  const float* __restrict__ bih0, const float* __restrict__ bhh0,
                  const float* __restrict__ Wih1, const float* __restrict__ Whh1,
                  const float* __restrict__ bih1, const float* __restrict__ bhh1,
                  const float* __restrict__ Wih2, const float* __restrict__ Whh2,
                  const float* __restrict__ bih2, const float* __restrict__ bhh2,
                  const float* __restrict__ fc1w, const float* __restrict__ fc1b,
                  const float* __restrict__ fc2w, const float* __restrict__ fc2b,
                  float* __restrict__ out,
                  float* __restrict__ fbuf, __hip_bfloat16* __restrict__ bbuf,
                  int use_bf16)
{
    __shared__ __align__(16) float xg_s[CHUNK][GDIM];    // 32 KB: chunk of input projections
    __shared__ __align__(16) float xin_s[CHUNK][HDIM];   // 8 KB: chunk of below-layer h
    __shared__ __align__(16) float xs_s[CHUNK];          // layer-0 scalar inputs
    __shared__ __align__(16) float h_s[HDIM];
    __shared__ __align__(16) float gates_s[GDIM];
    __shared__ __align__(16) float z_s[64];

    const int tid = threadIdx.x;          // gate row j in [0,512)
    const int b = blockIdx.x;             // batch element

    const float* WihL[3] = {Wih0, Wih1, Wih2};
    const float* WhhL[3] = {Whh0, Whh1, Whh2};
    const float* bihL[3] = {bih0, bih1, bih2};
    const float* bhhL[3] = {bhh0, bhh1, bhh2};

    float4 whh[HDIM / 4];   // register-resident Whh row for this thread's gate
    float c = 0.0f;         // cell state, owned by threads 0..127

#pragma unroll 1
    for (int layer = 0; layer < 3; ++layer) {
        const int in_dim = (layer == 0) ? 1 : HDIM;
        const float* Wih = WihL[layer];
        const float bsum = bihL[layer][tid] + bhhL[layer][tid];

        {
            const float4* wr = (const float4*)(WhhL[layer] + (size_t)tid * HDIM);
#pragma unroll
            for (int k = 0; k < HDIM / 4; ++k) whh[k] = wr[k];
        }

        if (tid < HDIM) h_s[tid] = 0.0f;
        c = 0.0f;
        __syncthreads();

#pragma unroll 1
        for (int t0 = 0; t0 < TDIM; t0 += CHUNK) {
            // ---- stage input chunk into LDS ----
            if (in_dim == 1) {
                if (tid < CHUNK) xs_s[tid] = x[(size_t)b * TDIM + t0 + tid];
            } else {
                if (use_bf16) {
                    const __hip_bfloat162* src =
                        (const __hip_bfloat162*)(bbuf + (size_t)b * TDIM * HDIM + (size_t)t0 * HDIM);
                    float* dst = &xin_s[0][0];
#pragma unroll
                    for (int i = 0; i < (CHUNK * HDIM / 2) / NT; ++i) {
                        int idx = i * NT + tid;
                        float2 f = __bfloat1622float2(src[idx]);
                        dst[2 * idx] = f.x;
                        dst[2 * idx + 1] = f.y;
                    }
                } else {
                    const float4* src =
                        (const float4*)(fbuf + (size_t)b * TDIM * HDIM + (size_t)t0 * HDIM);
                    float4* dst = (float4*)&xin_s[0][0];
#pragma unroll
                    for (int i = 0; i < (CHUNK * HDIM / 4) / NT; ++i) {
                        dst[i * NT + tid] = src[i * NT + tid];
                    }
                }
            }
            __syncthreads();

            // ---- input projection for this chunk -> xg_s ----
            if (in_dim == 1) {
                float w0 = Wih[tid];  // (4H,1)
#pragma unroll
                for (int tt = 0; tt < CHUNK; ++tt)
                    xg_s[tt][tid] = bsum + xs_s[tt] * w0;
            } else {
                float acc[CHUNK];
#pragma unroll
                for (int tt = 0; tt < CHUNK; ++tt) acc[tt] = bsum;
                const float4* wih4 = (const float4*)(Wih + (size_t)tid * HDIM);
#pragma unroll 1
                for (int kk = 0; kk < HDIM / 4; kk += 4) {
                    float4 w0 = wih4[kk + 0];
                    float4 w1 = wih4[kk + 1];
                    float4 w2 = wih4[kk + 2];
                    float4 w3 = wih4[kk + 3];
#pragma unroll
                    for (int tt = 0; tt < CHUNK; ++tt) {
                        const float4* xr = (const float4*)&xin_s[tt][kk * 4];
                        float4 x0 = xr[0], x1 = xr[1], x2 = xr[2], x3 = xr[3];
                        float s0 = x0.x * w0.x + x0.y * w0.y + x0.z * w0.z + x0.w * w0.w;
                        float s1 = x1.x * w1.x + x1.y * w1.y + x1.z * w1.z + x1.w * w1.w;
                        float s2 = x2.x * w2.x + x2.y * w2.y + x2.z * w2.z + x2.w * w2.w;
                        float s3 = x3.x * w3.x + x3.y * w3.y + x3.z * w3.z + x3.w * w3.w;
                        acc[tt] += (s0 + s1) + (s2 + s3);
                    }
                }
#pragma unroll
                for (int tt = 0; tt < CHUNK; ++tt) xg_s[tt][tid] = acc[tt];
            }
            __syncthreads();

            // ---- recurrence over the chunk ----
#pragma unroll 1
            for (int tt = 0; tt < CHUNK; ++tt) {
                const float4* h4 = (const float4*)h_s;
                float g0 = 0.f, g1 = 0.f, g2 = 0.f, g3 = 0.f;
#pragma unroll
                for (int k = 0; k < HDIM / 4; k += 4) {
                    float4 ha = h4[k + 0], hb = h4[k + 1], hc = h4[k + 2], hd = h4[k + 3];
                    g0 += ha.x * whh[k + 0].x + ha.y * whh[k + 0].y + ha.z * whh[k + 0].z + ha.w * whh[k + 0].w;
                    g1 += hb.x * whh[k + 1].x + hb.y * whh[k + 1].y + hb.z * whh[k + 1].z + hb.w * whh[k + 1].w;
                    g2 += hc.x * whh[k + 2].x + hc.y * whh[k + 2].y + hc.z * whh[k + 2].z + hc.w * whh[k + 2].w;
                    g3 += hd.x * whh[k + 3].x + hd.y * whh[k + 3].y + hd.z * whh[k + 3].z + hd.w * whh[k + 3].w;
                }
                float g = ((g0 + g1) + (g2 + g3)) + xg_s[tt][tid];
                // gate order i,f,g,o: tanh only for rows [256,384) -> wave-uniform branch
                float a = ((tid >> 7) == 2) ? tanh_f(g) : sigm_f(g);
                gates_s[tid] = a;
                __syncthreads();
                if (tid < HDIM) {
                    float gi = gates_s[tid];
                    float gf = gates_s[HDIM + tid];
                    float gg = gates_s[2 * HDIM + tid];
                    float go = gates_s[3 * HDIM + tid];
                    c = gf * c + gi * gg;
                    float h = go * tanh_f(c);
                    h_s[tid] = h;
                    if (layer < 2) {
                        size_t idx = (size_t)b * TDIM * HDIM + (size_t)(t0 + tt) * HDIM + tid;
                        if (use_bf16) bbuf[idx] = __float2bfloat16(h);
                        else fbuf[idx] = h;
                    }
                }
                __syncthreads();
            }
        }
    }

    // ---- FC head: out = relu(hT @ fc1_w.T + fc1_b) @ fc2_w.T + fc2_b ----
    if (tid < 64) {
        const float* w = fc1w + tid * HDIM;
        float s = fc1b[tid];
#pragma unroll
        for (int k = 0; k < HDIM; ++k) s += w[k] * h_s[k];
        z_s[tid] = fmaxf(s, 0.0f);
    }
    __syncthreads();
    if (tid < 5) {
        const float* w = fc2w + tid * 64;
        float s = fc2b[tid];
#pragma unroll
        for (int k = 0; k < 64; ++k) s += w[k] * z_s[k];
        out[b * 5 + tid] = s;
    }
}

extern "C" void kernel_launch(void* const* d_in, const int* in_sizes, int n_in,
                              void* d_out, int out_size, void* d_ws, size_t ws_size,
                              hipStream_t stream) {
    (void)in_sizes; (void)n_in; (void)out_size;
    const float* x    = (const float*)d_in[0];
    const float* Wih0 = (const float*)d_in[1];
    const float* Whh0 = (const float*)d_in[2];
    const float* bih0 = (const float*)d_in[3];
    const float* bhh0 = (const float*)d_in[4];
    const float* Wih1 = (const float*)d_in[5];
    const float* Whh1 = (const float*)d_in[6];
    const float* bih1 = (const float*)d_in[7];
    const float* bhh1 = (const float*)d_in[8];
    const float* Wih2 = (const float*)d_in[9];
    const float* Whh2 = (const float*)d_in[10];
    const float* bih2 = (const float*)d_in[11];
    const float* bhh2 = (const float*)d_in[12];
    const float* fc1w = (const float*)d_in[13];
    const float* fc1b = (const float*)d_in[14];
    const float* fc2w = (const float*)d_in[15];
    const float* fc2b = (const float*)d_in[16];
    float* out = (float*)d_out;

    // inter-layer (B,T,H) buffer lives in workspace; fp32 preferred, bf16 fallback
    size_t need_f32 = (size_t)BDIM * TDIM * HDIM * sizeof(float);  // 256 MB
    int use_bf16 = (ws_size < need_f32) ? 1 : 0;

    hipLaunchKernelGGL(lstm3_kernel, dim3(BDIM), dim3(NT), 0, stream,
                       x, Wih0, Whh0, bih0, bhh0,
                       Wih1, Whh1, bih1, bhh1,
                       Wih2, Whh2, bih2, bhh2,
                       fc1w, fc1b, fc2w, fc2b,
                       out, (float*)d_ws, (__hip_bfloat16*)d_ws, use_bf16);
}

// Round 2
// 6920.551 us; speedup vs baseline: 1.3840x; 1.3840x over previous
//
#include <hip/hip_runtime.h>
#include <hip/hip_bf16.h>

#define HDIM 128
#define TDIM 2048
#define BDIM 256
#define CHUNK 8
#define NT 512

typedef _Float16 half2_t __attribute__((ext_vector_type(2)));
typedef _Float16 half8_t __attribute__((ext_vector_type(8)));

#if defined(__has_builtin) && __has_builtin(__builtin_amdgcn_fdot2)
__device__ __forceinline__ float fdot2(half2_t a, half2_t b, float c) {
    return __builtin_amdgcn_fdot2(a, b, c, false);
}
#else
__device__ __forceinline__ float fdot2(half2_t a, half2_t b, float c) {
    return fmaf((float)a[0], (float)b[0], fmaf((float)a[1], (float)b[1], c));
}
#endif

__device__ __forceinline__ half2_t pick2(half8_t v, int k) {
    half2_t r; r[0] = v[2 * k]; r[1] = v[2 * k + 1]; return r;
}

__device__ __forceinline__ float sigm_f(float x) { return 1.0f / (1.0f + __expf(-x)); }
__device__ __forceinline__ float tanh_f(float x) { return 1.0f - 2.0f / (1.0f + __expf(2.0f * x)); }

__global__ __launch_bounds__(NT, 2)
void lstm3_kernel(const float* __restrict__ x,
                  const float* __restrict__ Wih0, const float* __restrict__ Whh0,
                  const float* __restrict__ bih0, const float* __restrict__ bhh0,
                  const float* __restrict__ Wih1, const float* __restrict__ Whh1,
                  const float* __restrict__ bih1, const float* __restrict__ bhh1,
                  const float* __restrict__ Wih2, const float* __restrict__ Whh2,
                  const float* __restrict__ bih2, const float* __restrict__ bhh2,
                  const float* __restrict__ fc1w, const float* __restrict__ fc1b,
                  const float* __restrict__ fc2w, const float* __restrict__ fc2b,
                  float* __restrict__ out, _Float16* __restrict__ gbuf)
{
    __shared__ __align__(16) _Float16 h_s[2][HDIM];        // ping-pong hidden state (fp16)
    __shared__ __align__(16) _Float16 xin_s[CHUNK][HDIM];  // staged below-layer h chunk
    __shared__ __align__(16) _Float16 hout_s[CHUNK][HDIM]; // produced h chunk (deferred store)
    __shared__ __align__(16) float xs_s[CHUNK];            // layer-0 scalar inputs
    __shared__ __align__(16) float z_s[64];

    const int tid = threadIdx.x;
    const int u = tid >> 2;   // hidden unit [0,128)
    const int p = tid & 3;    // K-quarter / quad lane [0,4)
    const int b = blockIdx.x;

    const float* WihL[3] = {Wih0, Wih1, Wih2};
    const float* WhhL[3] = {Whh0, Whh1, Whh2};
    const float* bihL[3] = {bih0, bih1, bih2};
    const float* bhhL[3] = {bhh0, bhh1, bhh2};

    // per-thread weight fragments: 4 gates x 32-element K-quarter, fp16 pairs
    half2_t whh[4][16];
    half2_t wih[4][16];

#pragma unroll 1
    for (int layer = 0; layer < 3; ++layer) {
        float bsum[4], w0[4];
#pragma unroll
        for (int q = 0; q < 4; ++q) {
            const int row = q * HDIM + u;
            bsum[q] = bihL[layer][row] + bhhL[layer][row];
            const float2* wr = (const float2*)(WhhL[layer] + (size_t)row * HDIM + p * 32);
#pragma unroll
            for (int j = 0; j < 16; ++j) {
                float2 f = wr[j];
                half2_t hv; hv[0] = (_Float16)f.x; hv[1] = (_Float16)f.y;
                whh[q][j] = hv;
            }
            if (layer > 0) {
                const float2* wr2 = (const float2*)(WihL[layer] + (size_t)row * HDIM + p * 32);
#pragma unroll
                for (int j = 0; j < 16; ++j) {
                    float2 f = wr2[j];
                    half2_t hv; hv[0] = (_Float16)f.x; hv[1] = (_Float16)f.y;
                    wih[q][j] = hv;
                }
            } else {
                w0[q] = Wih0[row];
            }
        }

        if (tid < HDIM) h_s[0][tid] = (_Float16)0.0f;
        float c = 0.0f;
        __syncthreads();

#pragma unroll 1
        for (int t0 = 0; t0 < TDIM; t0 += CHUNK) {
            // ---- stage input chunk ----
            if (layer == 0) {
                if (tid < CHUNK) xs_s[tid] = x[(size_t)b * TDIM + t0 + tid];
            } else {
                const int* src = (const int*)(gbuf + ((size_t)b * TDIM + t0) * HDIM);
                ((int*)&xin_s[0][0])[tid] = src[tid];   // 512 dwords = full 2KB chunk
            }
            __syncthreads();

            // ---- input projection -> register xg (acc), quad K-split ----
            float acc[CHUNK][4];
            if (layer == 0) {
#pragma unroll
                for (int tt = 0; tt < CHUNK; ++tt) {
                    float xv = xs_s[tt];
#pragma unroll
                    for (int q = 0; q < 4; ++q) acc[tt][q] = xv * w0[q];
                }
            } else {
#pragma unroll
                for (int tt = 0; tt < CHUNK; ++tt) {
                    const half8_t* xv = (const half8_t*)&xin_s[tt][p * 32];
                    half8_t x0 = xv[0], x1 = xv[1], x2 = xv[2], x3 = xv[3];
#pragma unroll
                    for (int q = 0; q < 4; ++q) {
                        float a0 = 0.0f, a1 = 0.0f;
#pragma unroll
                        for (int j = 0; j < 4; ++j) {
                            a0 = fdot2(pick2(x0, j), wih[q][j],      a0);
                            a0 = fdot2(pick2(x1, j), wih[q][4 + j],  a0);
                            a1 = fdot2(pick2(x2, j), wih[q][8 + j],  a1);
                            a1 = fdot2(pick2(x3, j), wih[q][12 + j], a1);
                        }
                        acc[tt][q] = a0 + a1;
                    }
                }
                // quad butterfly: full xg on all 4 lanes
#pragma unroll
                for (int tt = 0; tt < CHUNK; ++tt) {
#pragma unroll
                    for (int q = 0; q < 4; ++q) {
                        float a = acc[tt][q];
                        a += __shfl_xor(a, 1);
                        a += __shfl_xor(a, 2);
                        acc[tt][q] = a;
                    }
                }
            }

            // ---- recurrence over chunk: 1 barrier/step (ping-pong h_s) ----
#pragma unroll
            for (int tt = 0; tt < CHUNK; ++tt) {
                const int t = t0 + tt;
                const int rb = t & 1;
                const half8_t* hv = (const half8_t*)&h_s[rb][p * 32];
                half8_t h0 = hv[0], h1 = hv[1], h2v = hv[2], h3v = hv[3];
                float P[4];
#pragma unroll
                for (int q = 0; q < 4; ++q) {
                    float a0 = 0.0f, a1 = 0.0f;
#pragma unroll
                    for (int j = 0; j < 4; ++j) {
                        a0 = fdot2(pick2(h0, j),  whh[q][j],      a0);
                        a0 = fdot2(pick2(h1, j),  whh[q][4 + j],  a0);
                        a1 = fdot2(pick2(h2v, j), whh[q][8 + j],  a1);
                        a1 = fdot2(pick2(h3v, j), whh[q][12 + j], a1);
                    }
                    P[q] = a0 + a1;
                }
#pragma unroll
                for (int q = 0; q < 4; ++q) P[q] += __shfl_xor(P[q], 1);
#pragma unroll
                for (int q = 0; q < 4; ++q) P[q] += __shfl_xor(P[q], 2);

                float gI = P[0] + acc[tt][0] + bsum[0];
                float gF = P[1] + acc[tt][1] + bsum[1];
                float gG = P[2] + acc[tt][2] + bsum[2];
                float gO = P[3] + acc[tt][3] + bsum[3];
                float ig = sigm_f(gI);
                float fg = sigm_f(gF);
                float gg = tanh_f(gG);
                float og = sigm_f(gO);
                c = fg * c + ig * gg;               // c replicated identically on quad
                float h = og * tanh_f(c);
                _Float16 h16 = (_Float16)h;
                if (p == 0) h_s[rb ^ 1][u] = h16;
                if (layer < 2 && p == 1) hout_s[tt][u] = h16;
                __syncthreads();
            }

            // ---- deferred chunk store of produced h (layers 0,1) ----
            if (layer < 2) {
                int* dst = (int*)(gbuf + ((size_t)b * TDIM + t0) * HDIM);
                dst[tid] = ((const int*)&hout_s[0][0])[tid];
            }
        }
    }

    // ---- FC head: final h (t=2048, parity 0) in h_s[0] as fp16 ----
    if (tid < 64) {
        const float* w = fc1w + tid * HDIM;
        float s = fc1b[tid];
#pragma unroll
        for (int k = 0; k < HDIM; ++k) s += w[k] * (float)h_s[0][k];
        z_s[tid] = fmaxf(s, 0.0f);
    }
    __syncthreads();
    if (tid < 5) {
        const float* w = fc2w + tid * 64;
        float s = fc2b[tid];
#pragma unroll
        for (int k = 0; k < 64; ++k) s += w[k] * z_s[k];
        out[b * 5 + tid] = s;
    }
}

extern "C" void kernel_launch(void* const* d_in, const int* in_sizes, int n_in,
                              void* d_out, int out_size, void* d_ws, size_t ws_size,
                              hipStream_t stream) {
    (void)in_sizes; (void)n_in; (void)out_size; (void)ws_size;
    const float* x    = (const float*)d_in[0];
    const float* Wih0 = (const float*)d_in[1];
    const float* Whh0 = (const float*)d_in[2];
    const float* bih0 = (const float*)d_in[3];
    const float* bhh0 = (const float*)d_in[4];
    const float* Wih1 = (const float*)d_in[5];
    const float* Whh1 = (const float*)d_in[6];
    const float* bih1 = (const float*)d_in[7];
    const float* bhh1 = (const float*)d_in[8];
    const float* Wih2 = (const float*)d_in[9];
    const float* Whh2 = (const float*)d_in[10];
    const float* bih2 = (const float*)d_in[11];
    const float* bhh2 = (const float*)d_in[12];
    const float* fc1w = (const float*)d_in[13];
    const float* fc1b = (const float*)d_in[14];
    const float* fc2w = (const float*)d_in[15];
    const float* fc2b = (const float*)d_in[16];
    float* out = (float*)d_out;

    hipLaunchKernelGGL(lstm3_kernel, dim3(BDIM), dim3(NT), 0, stream,
                       x, Wih0, Whh0, bih0, bhh0,
                       Wih1, Whh1, bih1, bhh1,
                       Wih2, Whh2, bih2, bhh2,
                       fc1w, fc1b, fc2w, fc2b,
                       out, (_Float16*)d_ws);
}

// Round 3
// 6028.343 us; speedup vs baseline: 1.5889x; 1.1480x over previous
//
#include <hip/hip_runtime.h>
#include <hip/hip_bf16.h>

#define HDIM 128
#define TDIM 2048
#define BDIM 256
#define CHUNK 8
#define NT 512

typedef _Float16 half2_t __attribute__((ext_vector_type(2)));
typedef _Float16 half8_t __attribute__((ext_vector_type(8)));

#if defined(__has_builtin) && __has_builtin(__builtin_amdgcn_fdot2)
__device__ __forceinline__ float fdot2(half2_t a, half2_t b, float c) {
    return __builtin_amdgcn_fdot2(a, b, c, false);
}
#else
__device__ __forceinline__ float fdot2(half2_t a, half2_t b, float c) {
    return fmaf((float)a[0], (float)b[0], fmaf((float)a[1], (float)b[1], c));
}
#endif

__device__ __forceinline__ half2_t pick2(half8_t v, int k) {
    half2_t r; r[0] = v[2 * k]; r[1] = v[2 * k + 1]; return r;
}

// Butterfly sum across the DPP quad (lanes 4k..4k+3): all 4 lanes get the total.
// quad_perm[1,0,3,2] = 0xB1 (xor 1), quad_perm[2,3,0,1] = 0x4E (xor 2).
__device__ __forceinline__ float quad_sum(float v) {
    int i = __builtin_bit_cast(int, v);
    int a = __builtin_amdgcn_update_dpp(0, i, 0xB1, 0xF, 0xF, true);
    v += __builtin_bit_cast(float, a);
    i = __builtin_bit_cast(int, v);
    int b = __builtin_amdgcn_update_dpp(0, i, 0x4E, 0xF, 0xF, true);
    v += __builtin_bit_cast(float, b);
    return v;
}

__device__ __forceinline__ float sigm_f(float x) { return 1.0f / (1.0f + __expf(-x)); }
__device__ __forceinline__ float tanh_f(float x) { return 1.0f - 2.0f / (1.0f + __expf(2.0f * x)); }

__global__ __launch_bounds__(NT, 2)
void lstm3_kernel(const float* __restrict__ x,
                  const float* __restrict__ Wih0, const float* __restrict__ Whh0,
                  const float* __restrict__ bih0, const float* __restrict__ bhh0,
                  const float* __restrict__ Wih1, const float* __restrict__ Whh1,
                  const float* __restrict__ bih1, const float* __restrict__ bhh1,
                  const float* __restrict__ Wih2, const float* __restrict__ Whh2,
                  const float* __restrict__ bih2, const float* __restrict__ bhh2,
                  const float* __restrict__ fc1w, const float* __restrict__ fc1b,
                  const float* __restrict__ fc2w, const float* __restrict__ fc2b,
                  float* __restrict__ out, _Float16* __restrict__ gbuf)
{
    __shared__ __align__(16) _Float16 h_s[2][HDIM];        // ping-pong hidden state (fp16)
    __shared__ __align__(16) _Float16 xin_s[CHUNK][HDIM];  // staged below-layer h chunk
    __shared__ __align__(16) _Float16 hout_s[CHUNK][HDIM]; // produced h chunk (deferred store)
    __shared__ __align__(16) float xs_s[CHUNK];            // layer-0 scalar inputs
    __shared__ __align__(16) float z_s[64];

    const int tid = threadIdx.x;
    const int u = tid >> 2;   // hidden unit [0,128)
    const int p = tid & 3;    // K-quarter / DPP-quad lane [0,4)
    const int b = blockIdx.x;

    const float* WihL[3] = {Wih0, Wih1, Wih2};
    const float* WhhL[3] = {Whh0, Whh1, Whh2};
    const float* bihL[3] = {bih0, bih1, bih2};
    const float* bhhL[3] = {bhh0, bhh1, bhh2};

    // per-thread weight fragments: 4 gates x 32-element K-quarter, fp16 pairs
    half2_t whh[4][16];
    half2_t wih[4][16];

#pragma unroll 1
    for (int layer = 0; layer < 3; ++layer) {
        float bsum[4], w0[4];
#pragma unroll
        for (int q = 0; q < 4; ++q) {
            const int row = q * HDIM + u;
            bsum[q] = bihL[layer][row] + bhhL[layer][row];
            const float2* wr = (const float2*)(WhhL[layer] + (size_t)row * HDIM + p * 32);
#pragma unroll
            for (int j = 0; j < 16; ++j) {
                float2 f = wr[j];
                half2_t hv; hv[0] = (_Float16)f.x; hv[1] = (_Float16)f.y;
                whh[q][j] = hv;
            }
            if (layer > 0) {
                const float2* wr2 = (const float2*)(WihL[layer] + (size_t)row * HDIM + p * 32);
#pragma unroll
                for (int j = 0; j < 16; ++j) {
                    float2 f = wr2[j];
                    half2_t hv; hv[0] = (_Float16)f.x; hv[1] = (_Float16)f.y;
                    wih[q][j] = hv;
                }
            } else {
                w0[q] = Wih0[row];
            }
        }

        if (tid < HDIM) h_s[0][tid] = (_Float16)0.0f;
        float c = 0.0f;

        // ---- prefetch chunk 0 staging into registers ----
        int stage = 0;
        float xpre = 0.0f;
        if (layer == 0) {
            if (tid < CHUNK) xpre = x[(size_t)b * TDIM + tid];
        } else {
            stage = ((const int*)(gbuf + (size_t)b * TDIM * HDIM))[tid];
        }
        __syncthreads();

#pragma unroll 1
        for (int t0 = 0; t0 < TDIM; t0 += CHUNK) {
            // ---- commit staged chunk to LDS; prefetch next chunk ----
            if (layer == 0) {
                if (tid < CHUNK) xs_s[tid] = xpre;
            } else {
                ((int*)&xin_s[0][0])[tid] = stage;
            }
            {
                // clamp so the tail prefetch stays in-bounds (value unused)
                int tn = (t0 + CHUNK < TDIM) ? (t0 + CHUNK) : t0;
                if (layer == 0) {
                    if (tid < CHUNK) xpre = x[(size_t)b * TDIM + tn + tid];
                } else {
                    stage = ((const int*)(gbuf + ((size_t)b * TDIM + tn) * HDIM))[tid];
                }
            }
            __syncthreads();

            // ---- input projection -> register xg (acc), quad K-split ----
            float acc[CHUNK][4];
            if (layer == 0) {
#pragma unroll
                for (int tt = 0; tt < CHUNK; ++tt) {
                    float xv = xs_s[tt];
#pragma unroll
                    for (int q = 0; q < 4; ++q) acc[tt][q] = xv * w0[q];
                }
            } else {
#pragma unroll
                for (int tt = 0; tt < CHUNK; ++tt) {
                    const half8_t* xv = (const half8_t*)&xin_s[tt][p * 32];
                    half8_t x0 = xv[0], x1 = xv[1], x2 = xv[2], x3 = xv[3];
#pragma unroll
                    for (int q = 0; q < 4; ++q) {
                        float a0 = 0.0f, a1 = 0.0f;
#pragma unroll
                        for (int j = 0; j < 4; ++j) {
                            a0 = fdot2(pick2(x0, j), wih[q][j],      a0);
                            a0 = fdot2(pick2(x1, j), wih[q][4 + j],  a0);
                            a1 = fdot2(pick2(x2, j), wih[q][8 + j],  a1);
                            a1 = fdot2(pick2(x3, j), wih[q][12 + j], a1);
                        }
                        acc[tt][q] = a0 + a1;
                    }
                }
                // DPP quad butterfly: full xg on all 4 lanes, no DS pipe
#pragma unroll
                for (int tt = 0; tt < CHUNK; ++tt)
#pragma unroll
                    for (int q = 0; q < 4; ++q)
                        acc[tt][q] = quad_sum(acc[tt][q]);
            }

            // ---- recurrence over chunk: 1 barrier/step (ping-pong h_s) ----
#pragma unroll
            for (int tt = 0; tt < CHUNK; ++tt) {
                const int t = t0 + tt;
                const int rb = t & 1;
                const half8_t* hv = (const half8_t*)&h_s[rb][p * 32];
                half8_t h0 = hv[0], h1 = hv[1], h2v = hv[2], h3v = hv[3];
                float P[4];
#pragma unroll
                for (int q = 0; q < 4; ++q) {
                    float a0 = 0.0f, a1 = 0.0f;
#pragma unroll
                    for (int j = 0; j < 4; ++j) {
                        a0 = fdot2(pick2(h0, j),  whh[q][j],      a0);
                        a0 = fdot2(pick2(h1, j),  whh[q][4 + j],  a0);
                        a1 = fdot2(pick2(h2v, j), whh[q][8 + j],  a1);
                        a1 = fdot2(pick2(h3v, j), whh[q][12 + j], a1);
                    }
                    P[q] = a0 + a1;
                }
#pragma unroll
                for (int q = 0; q < 4; ++q) P[q] = quad_sum(P[q]);

                float gI = P[0] + acc[tt][0] + bsum[0];
                float gF = P[1] + acc[tt][1] + bsum[1];
                float gG = P[2] + acc[tt][2] + bsum[2];
                float gO = P[3] + acc[tt][3] + bsum[3];
                float ig = sigm_f(gI);
                float fg = sigm_f(gF);
                float gg = tanh_f(gG);
                float og = sigm_f(gO);
                c = fg * c + ig * gg;               // c replicated identically on quad
                float h = og * tanh_f(c);
                _Float16 h16 = (_Float16)h;
                if (p == 0) h_s[rb ^ 1][u] = h16;
                if (layer < 2 && p == 1) hout_s[tt][u] = h16;
                __syncthreads();
            }

            // ---- deferred chunk store of produced h (layers 0,1) ----
            if (layer < 2) {
                int* dst = (int*)(gbuf + ((size_t)b * TDIM + t0) * HDIM);
                dst[tid] = ((const int*)&hout_s[0][0])[tid];
            }
        }
    }

    // ---- FC head: final h (t=2048, parity 0) in h_s[0] as fp16 ----
    if (tid < 64) {
        const float* w = fc1w + tid * HDIM;
        float s = fc1b[tid];
#pragma unroll
        for (int k = 0; k < HDIM; ++k) s += w[k] * (float)h_s[0][k];
        z_s[tid] = fmaxf(s, 0.0f);
    }
    __syncthreads();
    if (tid < 5) {
        const float* w = fc2w + tid * 64;
        float s = fc2b[tid];
#pragma unroll
        for (int k = 0; k < 64; ++k) s += w[k] * z_s[k];
        out[b * 5 + tid] = s;
    }
}

extern "C" void kernel_launch(void* const* d_in, const int* in_sizes, int n_in,
                              void* d_out, int out_size, void* d_ws, size_t ws_size,
                              hipStream_t stream) {
    (void)in_sizes; (void)n_in; (void)out_size; (void)ws_size;
    const float* x    = (const float*)d_in[0];
    const float* Wih0 = (const float*)d_in[1];
    const float* Whh0 = (const float*)d_in[2];
    const float* bih0 = (const float*)d_in[3];
    const float* bhh0 = (const float*)d_in[4];
    const float* Wih1 = (const float*)d_in[5];
    const float* Whh1 = (const float*)d_in[6];
    const float* bih1 = (const float*)d_in[7];
    const float* bhh1 = (const float*)d_in[8];
    const float* Wih2 = (const float*)d_in[9];
    const float* Whh2 = (const float*)d_in[10];
    const float* bih2 = (const float*)d_in[11];
    const float* bhh2 = (const float*)d_in[12];
    const float* fc1w = (const float*)d_in[13];
    const float* fc1b = (const float*)d_in[14];
    const float* fc2w = (const float*)d_in[15];
    const float* fc2b = (const float*)d_in[16];
    float* out = (float*)d_out;

    hipLaunchKernelGGL(lstm3_kernel, dim3(BDIM), dim3(NT), 0, stream,
                       x, Wih0, Whh0, bih0, bhh0,
                       Wih1, Whh1, bih1, bhh1,
                       Wih2, Whh2, bih2, bhh2,
                       fc1w, fc1b, fc2w, fc2b,
                       out, (_Float16*)d_ws);
}